// Round 5
// baseline (161.537 us; speedup 1.0000x reference)
//
#include <hip/hip_runtime.h>
#include <hip/hip_bf16.h>
#include <math.h>

// Problem constants
#define BB 2
#define SS 2048
#define DD 512
#define MTOT 4096   // B*S

typedef __attribute__((ext_vector_type(8))) short sv8;   // 8 bf16
typedef __attribute__((ext_vector_type(4))) float f32x4;

// workspace layout (bytes)
static const size_t OFF_XB   = 0;               // bf16 x      [4096][512]   4 MB (dead after gemms on xb)
static const size_t OFF_WT   = 4194304;         // bf16 Wt     [5][512][512] 2.5 MB ([q|k|r|v|o], [n][k])
static const size_t OFF_BIAS = 6815744;         // f32 bias    [2048]        8 KB (bq|bk|br|bv)
static const size_t OFF_Y    = 6823936;         // bf16 Y      [4096][1536]  12 MB (q|k|sence)
static const size_t OFF_VT   = 19406848;        // bf16 Vt     [2][512][2048] 4 MB (v transposed)
static const size_t OFF_READ = 23601152;        // bf16 read   [4096][512]   4 MB
static const size_t OFF_ATT  = 0;               // bf16 att    [4096][512]   4 MB (reuses XB)

static __device__ __forceinline__ float bf2f(short s) {
    unsigned u = ((unsigned)(unsigned short)s) << 16;
    return __builtin_bit_cast(float, u);
}
static __device__ __forceinline__ short f2bf(float f) {
    unsigned u = __builtin_bit_cast(unsigned, f);
    unsigned r = 0x7fffu + ((u >> 16) & 1u);
    u += r;
    return (short)(u >> 16);
}

// async global->LDS, 16B per lane; LDS dest must be wave-uniform base (HW adds lane*16)
#define GLOAD_LDS16(gp, lp)                                                        \
    __builtin_amdgcn_global_load_lds(                                              \
        (const __attribute__((address_space(1))) unsigned*)(gp),                   \
        (__attribute__((address_space(3))) unsigned*)(lp), 16, 0, 0)

// ---------------- cast x to bf16 ----------------
__global__ __launch_bounds__(256) void cast_x(const float* __restrict__ x,
                                              short* __restrict__ xb, int n4) {
    int i = blockIdx.x * 256 + threadIdx.x;
    if (i < n4) {
        float4 v = ((const float4*)x)[i];
        short4 o;
        o.x = f2bf(v.x); o.y = f2bf(v.y); o.z = f2bf(v.z); o.w = f2bf(v.w);
        ((short4*)xb)[i] = o;
    }
}

// ------------- cast + transpose weights -> Wt[z][n][k] bf16; z order q,k,r,v,o -------------
__global__ __launch_bounds__(256) void cast_w(const float* __restrict__ Wq,
                                              const float* __restrict__ Wk,
                                              const float* __restrict__ Wr,
                                              const float* __restrict__ Wv,
                                              const float* __restrict__ Wo,
                                              short* __restrict__ wt) {
    __shared__ float tile[32][33];
    int z = blockIdx.z;
    const float* W = (z == 0) ? Wq : (z == 1) ? Wk : (z == 2) ? Wr : (z == 3) ? Wv : Wo;
    int k0 = blockIdx.y * 32, n0 = blockIdx.x * 32;
    int tx = threadIdx.x & 31, ty = threadIdx.x >> 5;  // ty in 0..7
    for (int r = ty; r < 32; r += 8)
        tile[r][tx] = W[(size_t)(k0 + r) * 512 + n0 + tx];
    __syncthreads();
    short* o = wt + (size_t)z * 512 * 512;
    for (int r = ty; r < 32; r += 8)
        o[(size_t)(n0 + r) * 512 + k0 + tx] = f2bf(tile[tx][r]);
}

// ------------- concat biases: bq|bk|br|bv -------------
__global__ __launch_bounds__(256) void prep_bias(const float* __restrict__ bq,
                                                 const float* __restrict__ bk,
                                                 const float* __restrict__ br,
                                                 const float* __restrict__ bv,
                                                 float* __restrict__ ball) {
    int i = blockIdx.x * 256 + threadIdx.x;  // 0..2047
    int sel = i >> 9;
    const float* src = (sel == 0) ? bq : (sel == 1) ? bk : (sel == 2) ? br : bv;
    ball[i] = src[i & 511];
}

// ------------- bf16 MFMA GEMM, global_load_lds staging, linear LDS -------------
// A: [M][512] bf16, Bt: [N][512] bf16. 128x128 tile, BK=64.
// MODE 0: Cout[row*ldc+col] = f2bf(acc + bias[col])
// MODE 1: transposed output (operand-swapped MFMA): Cout is Vt[2][512][2048];
//         d = nbase+frag-row (bias index dl), t = mbase + frag-col.
template <int MODE>
__global__ __launch_bounds__(256) void gemm_bt(const short* __restrict__ A,
                                               const short* __restrict__ Bt,
                                               const float* __restrict__ bias,
                                               short* __restrict__ Cout, int ldc) {
    __shared__ __align__(16) short lA[128 * 64];
    __shared__ __align__(16) short lB[128 * 64];
    int tid = threadIdx.x;
    int mbase = blockIdx.y * 128;
    int nbase = blockIdx.x * 128;
    int lane = tid & 63, wave = tid >> 6;
    int wm = wave >> 1, wn = wave & 1;

    f32x4 acc[4][4] = {};

    // per-lane global offsets for staging (wave-chunk linear LDS order)
    int srow = (lane >> 3);        // 0..7 within 8-row chunk
    int scol = (lane & 7) * 8;     // element offset (16B)

    for (int k0 = 0; k0 < 512; k0 += 64) {
#pragma unroll
        for (int c = 0; c < 4; ++c) {
            int ch = wave * 4 + c;  // 0..15, wave-uniform
            int row = ch * 8 + srow;
            GLOAD_LDS16(A + (size_t)(mbase + row) * 512 + k0 + scol, &lA[ch * 512]);
            GLOAD_LDS16(Bt + (size_t)(nbase + row) * 512 + k0 + scol, &lB[ch * 512]);
        }
        __syncthreads();
#pragma unroll
        for (int kk = 0; kk < 2; ++kk) {
            int koff = kk * 32 + (lane >> 4) * 8;
            sv8 af[4], bfr[4];
#pragma unroll
            for (int m = 0; m < 4; ++m)
                af[m] = *(const sv8*)&lA[(wm * 64 + m * 16 + (lane & 15)) * 64 + koff];
#pragma unroll
            for (int n = 0; n < 4; ++n)
                bfr[n] = *(const sv8*)&lB[(wn * 64 + n * 16 + (lane & 15)) * 64 + koff];
#pragma unroll
            for (int m = 0; m < 4; ++m)
#pragma unroll
                for (int n = 0; n < 4; ++n) {
                    if (MODE == 0)
                        acc[m][n] = __builtin_amdgcn_mfma_f32_16x16x32_bf16(
                            af[m], bfr[n], acc[m][n], 0, 0, 0);
                    else  // swapped: computes the transposed tile
                        acc[m][n] = __builtin_amdgcn_mfma_f32_16x16x32_bf16(
                            bfr[n], af[m], acc[m][n], 0, 0, 0);
                }
        }
        __syncthreads();
    }

    int r0 = (lane >> 4) * 4, c0 = lane & 15;
    if (MODE == 0) {
#pragma unroll
        for (int m = 0; m < 4; ++m)
#pragma unroll
            for (int n = 0; n < 4; ++n) {
                int col = nbase + wn * 64 + n * 16 + c0;
                float bv = bias[col];
#pragma unroll
                for (int j = 0; j < 4; ++j) {
                    int row = mbase + wm * 64 + m * 16 + r0 + j;
                    Cout[(size_t)row * ldc + col] = f2bf(acc[m][n][j] + bv);
                }
            }
    } else {
        // Vt[b][d][t]; frag row -> d, frag col -> t (coalesced 16-lane t runs)
        int bb = mbase >> 11, tb = mbase & 2047;
#pragma unroll
        for (int m = 0; m < 4; ++m)
#pragma unroll
            for (int n = 0; n < 4; ++n) {
                int dl = nbase + wn * 64 + n * 16 + r0;
                int tl = tb + wm * 64 + m * 16 + c0;
#pragma unroll
                for (int j = 0; j < 4; ++j) {
                    float v = acc[m][n][j] + bias[dl + j];
                    Cout[((size_t)bb * 512 + dl + j) * 2048 + tl] = f2bf(v);
                }
            }
    }
}

// ------------- fused local attention: QK^T + softmax (LDS) + PV -------------
// One block per 64-query tile; window of 128 keys: kr = t0-64+j, j=0..127.
// Y: [4096][1536] = [q|k|sence]; Vt: [2][512][2048]; att: [4096][512].
__global__ __launch_bounds__(256) void attn_fused(const short* __restrict__ Y,
                                                  const short* __restrict__ Vt,
                                                  short* __restrict__ att) {
    __shared__ float sS[64][132];
    __shared__ __align__(16) short sP[64 * 128];
    int tile = blockIdx.x;  // 0..63
    int b = tile >> 5;
    int t0 = (tile & 31) * 64;
    int s0 = tile * 64;
    int tid = threadIdx.x, lane = tid & 63, wave = tid >> 6;
    int wm = wave >> 1, wn = wave & 1;

    // ---- phase 1: S = Q K^T ----
    f32x4 acc[2][4] = {};
    const short* Q = Y;
    const short* Kb = Y + 512;
    int arow[2], brow[4];
#pragma unroll
    for (int m = 0; m < 2; ++m) arow[m] = s0 + wm * 32 + m * 16 + (lane & 15);
#pragma unroll
    for (int n = 0; n < 4; ++n) {
        int kr = t0 - 64 + wn * 64 + n * 16 + (lane & 15);
        if (kr < 0) kr = 0;  // masked later
        brow[n] = (b << 11) + kr;
    }
#pragma unroll
    for (int step = 0; step < 16; ++step) {
        int koff = step * 32 + (lane >> 4) * 8;
        sv8 af[2], bfr[4];
#pragma unroll
        for (int m = 0; m < 2; ++m)
            af[m] = *(const sv8*)(Q + (size_t)arow[m] * 1536 + koff);
#pragma unroll
        for (int n = 0; n < 4; ++n)
            bfr[n] = *(const sv8*)(Kb + (size_t)brow[n] * 1536 + koff);
#pragma unroll
        for (int m = 0; m < 2; ++m)
#pragma unroll
            for (int n = 0; n < 4; ++n)
                acc[m][n] = __builtin_amdgcn_mfma_f32_16x16x32_bf16(
                    af[m], bfr[n], acc[m][n], 0, 0, 0);
    }
    int r0 = (lane >> 4) * 4, c0 = lane & 15;
#pragma unroll
    for (int m = 0; m < 2; ++m)
#pragma unroll
        for (int n = 0; n < 4; ++n) {
            int jc = wn * 64 + n * 16 + c0;
#pragma unroll
            for (int j = 0; j < 4; ++j)
                sS[wm * 32 + m * 16 + r0 + j][jc] =
                    acc[m][n][j] * 0.04419417382415922f;  // 1/sqrt(512)
        }
    __syncthreads();

    // ---- softmax: thread -> (q = tid>>2, quarter = tid&3) ----
    {
        int q = tid >> 2, j0 = (tid & 3) * 32;
        float v[32];
        float mx = -1e30f;
        int jlo = q + 1;
        int jmin0 = 64 - t0;
        if (jmin0 > jlo) jlo = jmin0;
        int jhi = q + 64;
#pragma unroll
        for (int jj = 0; jj < 32; ++jj) {
            int j = j0 + jj;
            bool ok = (j >= jlo) && (j <= jhi);
            float s = ok ? sS[q][j] : -1e30f;
            v[jj] = s;
            mx = fmaxf(mx, s);
        }
        mx = fmaxf(mx, __shfl_xor(mx, 1));
        mx = fmaxf(mx, __shfl_xor(mx, 2));
        float sum = 0.f;
#pragma unroll
        for (int jj = 0; jj < 32; ++jj) {
            float e = (v[jj] > -1e29f) ? __expf(v[jj] - mx) : 0.f;
            v[jj] = e;
            sum += e;
        }
        sum += __shfl_xor(sum, 1);
        sum += __shfl_xor(sum, 2);
        float inv = 1.f / sum;
        short* dst = &sP[q * 128 + j0];
#pragma unroll
        for (int k = 0; k < 4; ++k) {
            sv8 o;
#pragma unroll
            for (int e = 0; e < 8; ++e) o[e] = f2bf(v[k * 8 + e] * inv);
            *(sv8*)(dst + k * 8) = o;
        }
    }
    __syncthreads();

    // ---- phase 2: att = P' @ V (wave = 128-d chunk) ----
    f32x4 acc2[4][8] = {};
    const short* Vb = Vt + (size_t)b * 512 * 2048;
#pragma unroll
    for (int ks = 0; ks < 4; ++ks) {
        int koff = ks * 32 + (lane >> 4) * 8;
        sv8 paf[4];
#pragma unroll
        for (int m = 0; m < 4; ++m)
            paf[m] = *(const sv8*)&sP[(m * 16 + (lane & 15)) * 128 + koff];
#pragma unroll
        for (int n = 0; n < 8; ++n) {
            int d = wave * 128 + n * 16 + (lane & 15);
            long off = (long)d * 2048 + (t0 - 64 + koff);  // may be <0 at t0=0 (P'=0 there)
            sv8 vv = *(const sv8*)(Vb + off);
#pragma unroll
            for (int m = 0; m < 4; ++m)
                acc2[m][n] = __builtin_amdgcn_mfma_f32_16x16x32_bf16(
                    paf[m], vv, acc2[m][n], 0, 0, 0);
        }
    }
#pragma unroll
    for (int m = 0; m < 4; ++m)
#pragma unroll
        for (int n = 0; n < 8; ++n) {
            int col = wave * 128 + n * 16 + c0;
#pragma unroll
            for (int j = 0; j < 4; ++j) {
                int row = s0 + m * 16 + r0 + j;
                att[(size_t)row * 512 + col] = f2bf(acc2[m][n][j]);
            }
        }
}

// ------------- LN(read) + LN(sence) + GeLU -------------
__global__ __launch_bounds__(256) void ln_gelu(const short* __restrict__ readb,
                                               const short* __restrict__ Y,
                                               const float* __restrict__ gamma,
                                               const float* __restrict__ beta,
                                               float* __restrict__ out) {
    int s = blockIdx.x;
    int tid = threadIdx.x;
    const short* r = readb + (size_t)s * 512;
    const short* sn = Y + (size_t)s * 1536 + 1024;
    float r0 = bf2f(r[tid]), r1 = bf2f(r[tid + 256]);
    float s0 = bf2f(sn[tid]), s1 = bf2f(sn[tid + 256]);

    float v0 = r0 + r1, v1 = r0 * r0 + r1 * r1;
    float v2 = s0 + s1, v3 = s0 * s0 + s1 * s1;
#pragma unroll
    for (int off = 32; off; off >>= 1) {
        v0 += __shfl_xor(v0, off);
        v1 += __shfl_xor(v1, off);
        v2 += __shfl_xor(v2, off);
        v3 += __shfl_xor(v3, off);
    }
    __shared__ float red[4][4];
    int wave = tid >> 6, lane = tid & 63;
    if (lane == 0) {
        red[wave][0] = v0; red[wave][1] = v1; red[wave][2] = v2; red[wave][3] = v3;
    }
    __syncthreads();
    float t0 = red[0][0] + red[1][0] + red[2][0] + red[3][0];
    float t1 = red[0][1] + red[1][1] + red[2][1] + red[3][1];
    float t2 = red[0][2] + red[1][2] + red[2][2] + red[3][2];
    float t3 = red[0][3] + red[1][3] + red[2][3] + red[3][3];

    float mu_r = t0 * (1.f / 512.f);
    float var_r = t1 * (1.f / 512.f) - mu_r * mu_r;
    float is_r = rsqrtf(var_r + 1e-5f);
    float mu_s = t2 * (1.f / 512.f);
    float var_s = t3 * (1.f / 512.f) - mu_s * mu_s;
    float is_s = rsqrtf(var_s + 1e-5f);

    float g0 = gamma[tid], be0 = beta[tid];
    float g1 = gamma[tid + 256], be1 = beta[tid + 256];
    float x0 = (r0 - mu_r) * is_r * g0 + be0 + (s0 - mu_s) * is_s * g0 + be0;
    float x1 = (r1 - mu_r) * is_r * g1 + be1 + (s1 - mu_s) * is_s * g1 + be1;
    float y0 = 0.5f * x0 * (1.f + erff(x0 * 0.70710678118654752f));
    float y1 = 0.5f * x1 * (1.f + erff(x1 * 0.70710678118654752f));
    out[(size_t)s * 512 + tid] = y0;
    out[(size_t)s * 512 + tid + 256] = y1;
}

extern "C" void kernel_launch(void* const* d_in, const int* in_sizes, int n_in,
                              void* d_out, int out_size, void* d_ws, size_t ws_size,
                              hipStream_t stream) {
    const float* x  = (const float*)d_in[0];
    const float* Wq = (const float*)d_in[1];
    const float* bq = (const float*)d_in[2];
    const float* Wk = (const float*)d_in[3];
    const float* bk = (const float*)d_in[4];
    const float* Wv = (const float*)d_in[5];
    const float* bv = (const float*)d_in[6];
    const float* Wo = (const float*)d_in[7];
    const float* bo = (const float*)d_in[8];
    const float* Wr = (const float*)d_in[9];
    const float* br = (const float*)d_in[10];
    const float* gamma = (const float*)d_in[11];
    const float* beta  = (const float*)d_in[12];

    char* ws = (char*)d_ws;
    short* xb    = (short*)(ws + OFF_XB);
    short* wt    = (short*)(ws + OFF_WT);
    float* ball  = (float*)(ws + OFF_BIAS);
    short* Y     = (short*)(ws + OFF_Y);
    short* vtb   = (short*)(ws + OFF_VT);
    short* att   = (short*)(ws + OFF_ATT);   // overlays xb (dead after gemms)
    short* readb = (short*)(ws + OFF_READ);

    cast_x<<<2048, 256, 0, stream>>>(x, xb, MTOT * DD / 4);
    cast_w<<<dim3(16, 16, 5), 256, 0, stream>>>(Wq, Wk, Wr, Wv, Wo, wt);
    prep_bias<<<8, 256, 0, stream>>>(bq, bk, br, bv, ball);

    // Y = [q|k|sence]
    gemm_bt<0><<<dim3(12, 32), 256, 0, stream>>>(xb, wt, ball, Y, 1536);
    // Vt = (x@Wv + bv)^T, written transposed via operand-swapped MFMA
    gemm_bt<1><<<dim3(4, 32), 256, 0, stream>>>(xb, wt + (size_t)3 * 512 * 512,
                                                ball + 1536, vtb, 0);

    attn_fused<<<64, 256, 0, stream>>>(Y, vtb, att);

    // read = att @ Wo + bo (bf16 out)
    gemm_bt<0><<<dim3(4, 32), 256, 0, stream>>>(att, wt + (size_t)4 * 512 * 512, bo,
                                                readb, 512);

    ln_gelu<<<4096, 256, 0, stream>>>(readb, Y, gamma, beta, (float*)d_out);
}

// Round 6
// 157.228 us; speedup vs baseline: 1.0274x; 1.0274x over previous
//
#include <hip/hip_runtime.h>
#include <hip/hip_bf16.h>
#include <math.h>

// Problem constants
#define BB 2
#define SS 2048
#define DD 512
#define MTOT 4096   // B*S

typedef __attribute__((ext_vector_type(8))) short sv8;   // 8 bf16
typedef __attribute__((ext_vector_type(4))) float f32x4;

// workspace layout (bytes)
static const size_t OFF_XB   = 0;               // bf16 x      [4096][512]   4 MB (dead after gemm1; att reuses)
static const size_t OFF_WT   = 4194304;         // bf16 Wt     [5][512][512] 2.5 MB ([q|k|v|r|o], [n][k])
static const size_t OFF_BIAS = 6815744;         // f32 bias    [2048]        8 KB (bq|bk|bv|br)
static const size_t OFF_Y    = 6823936;         // bf16 Y      [4096][1536]  12 MB (q|k|sence)
static const size_t OFF_VT   = 19406848;        // bf16 Vt     [2][512][2048] 4 MB (v transposed)
static const size_t OFF_READ = 23601152;        // bf16 read   [4096][512]   4 MB
static const size_t OFF_PP   = 27795456;        // bf16 P'     [64][64][128]  1 MB
static const size_t OFF_ATT  = 0;               // bf16 att    [4096][512]   4 MB (reuses XB)

static __device__ __forceinline__ float bf2f(short s) {
    unsigned u = ((unsigned)(unsigned short)s) << 16;
    return __builtin_bit_cast(float, u);
}
static __device__ __forceinline__ short f2bf(float f) {
    unsigned u = __builtin_bit_cast(unsigned, f);
    unsigned r = 0x7fffu + ((u >> 16) & 1u);
    u += r;
    return (short)(u >> 16);
}

// async global->LDS, 16B per lane; LDS dest is wave-uniform base (HW adds lane*16)
#define GLOAD_LDS16(gp, lp)                                                        \
    __builtin_amdgcn_global_load_lds(                                              \
        (const __attribute__((address_space(1))) unsigned*)(gp),                   \
        (__attribute__((address_space(3))) unsigned*)(lp), 16, 0, 0)

// ---------------- cast x to bf16 ----------------
__global__ __launch_bounds__(256) void cast_x(const float* __restrict__ x,
                                              short* __restrict__ xb, int n4) {
    int i = blockIdx.x * 256 + threadIdx.x;
    if (i < n4) {
        float4 v = ((const float4*)x)[i];
        short4 o;
        o.x = f2bf(v.x); o.y = f2bf(v.y); o.z = f2bf(v.z); o.w = f2bf(v.w);
        ((short4*)xb)[i] = o;
    }
}

// ------------- weights cast+transpose (z=0..4: q,k,v,r,o) + bias concat (z=5) -------------
__global__ __launch_bounds__(256) void prep_all(const float* __restrict__ Wq,
                                                const float* __restrict__ Wk,
                                                const float* __restrict__ Wv,
                                                const float* __restrict__ Wr,
                                                const float* __restrict__ Wo,
                                                const float* __restrict__ bq,
                                                const float* __restrict__ bk,
                                                const float* __restrict__ bv,
                                                const float* __restrict__ br,
                                                short* __restrict__ wt,
                                                float* __restrict__ ball) {
    int z = blockIdx.z;
    if (z == 5) {
        if (blockIdx.y != 0 || blockIdx.x >= 8) return;
        int i = blockIdx.x * 256 + threadIdx.x;  // 0..2047
        int sel = i >> 9;
        const float* src = (sel == 0) ? bq : (sel == 1) ? bk : (sel == 2) ? bv : br;
        ball[i] = src[i & 511];
        return;
    }
    __shared__ float tile[32][33];
    const float* W = (z == 0) ? Wq : (z == 1) ? Wk : (z == 2) ? Wv : (z == 3) ? Wr : Wo;
    int k0 = blockIdx.y * 32, n0 = blockIdx.x * 32;
    int tx = threadIdx.x & 31, ty = threadIdx.x >> 5;  // ty in 0..7
    for (int r = ty; r < 32; r += 8)
        tile[r][tx] = W[(size_t)(k0 + r) * 512 + n0 + tx];
    __syncthreads();
    short* o = wt + (size_t)z * 512 * 512;
    for (int r = ty; r < 32; r += 8)
        o[(size_t)(n0 + r) * 512 + k0 + tx] = f2bf(tile[tx][r]);
}

// ------------- bf16 MFMA GEMM, global_load_lds staging, linear LDS -------------
// A: [M][512] bf16, Bt: [N][512] bf16. 128x128 tile, BK=64.
// GEMM1==0: plain: Cout[row*ldc+col] = f2bf(acc + bias[col]).
// GEMM1==1: col remap for fused [q|k|v|r] output:
//   cols <1024 (q,k)  -> Y[row*1536 + col]
//   cols 1024..1535 (v) -> operand-swapped MFMA, transposed out to Vt[b][d][t]
//   cols >=1536 (r)    -> Y[row*1536 + col-512]
template <int GEMM1>
__global__ __launch_bounds__(256) void gemm_bt(const short* __restrict__ A,
                                               const short* __restrict__ Bt,
                                               const float* __restrict__ bias,
                                               short* __restrict__ Cout, int ldc,
                                               short* __restrict__ vt) {
    __shared__ __align__(16) short lA[128 * 64];
    __shared__ __align__(16) short lB[128 * 64];
    int tid = threadIdx.x;
    int mbase = blockIdx.y * 128;
    int nbase = blockIdx.x * 128;
    int lane = tid & 63, wave = tid >> 6;
    int wm = wave >> 1, wn = wave & 1;
    bool vswap = GEMM1 && (nbase >= 1024) && (nbase < 1536);

    f32x4 acc[4][4] = {};

    int srow = (lane >> 3);        // 0..7 within 8-row chunk
    int scol = (lane & 7) * 8;     // element offset (16B)

    for (int k0 = 0; k0 < 512; k0 += 64) {
#pragma unroll
        for (int c = 0; c < 4; ++c) {
            int ch = wave * 4 + c;  // 0..15, wave-uniform
            int row = ch * 8 + srow;
            GLOAD_LDS16(A + (size_t)(mbase + row) * 512 + k0 + scol, &lA[ch * 512]);
            GLOAD_LDS16(Bt + (size_t)(nbase + row) * 512 + k0 + scol, &lB[ch * 512]);
        }
        __syncthreads();
#pragma unroll
        for (int kk = 0; kk < 2; ++kk) {
            int koff = kk * 32 + (lane >> 4) * 8;
            sv8 af[4], bfr[4];
#pragma unroll
            for (int m = 0; m < 4; ++m)
                af[m] = *(const sv8*)&lA[(wm * 64 + m * 16 + (lane & 15)) * 64 + koff];
#pragma unroll
            for (int n = 0; n < 4; ++n)
                bfr[n] = *(const sv8*)&lB[(wn * 64 + n * 16 + (lane & 15)) * 64 + koff];
            if (!vswap) {
#pragma unroll
                for (int m = 0; m < 4; ++m)
#pragma unroll
                    for (int n = 0; n < 4; ++n)
                        acc[m][n] = __builtin_amdgcn_mfma_f32_16x16x32_bf16(
                            af[m], bfr[n], acc[m][n], 0, 0, 0);
            } else {  // swapped: acc holds the transposed tile
#pragma unroll
                for (int m = 0; m < 4; ++m)
#pragma unroll
                    for (int n = 0; n < 4; ++n)
                        acc[m][n] = __builtin_amdgcn_mfma_f32_16x16x32_bf16(
                            bfr[n], af[m], acc[m][n], 0, 0, 0);
            }
        }
        __syncthreads();
    }

    int r0 = (lane >> 4) * 4, c0 = lane & 15;
    if (!vswap) {
#pragma unroll
        for (int m = 0; m < 4; ++m)
#pragma unroll
            for (int n = 0; n < 4; ++n) {
                int col = nbase + wn * 64 + n * 16 + c0;
                float bv = bias[col];
                int ycol = (GEMM1 && col >= 1536) ? col - 512 : col;
#pragma unroll
                for (int j = 0; j < 4; ++j) {
                    int row = mbase + wm * 64 + m * 16 + r0 + j;
                    Cout[(size_t)row * ldc + ycol] = f2bf(acc[m][n][j] + bv);
                }
            }
    } else {
        // Vt[b][d][t]: frag rows -> d (feature), frag cols -> t (token, 16-lane contiguous)
        int bb = mbase >> 11, tb = mbase & 2047;
#pragma unroll
        for (int m = 0; m < 4; ++m)
#pragma unroll
            for (int n = 0; n < 4; ++n) {
                int dglob = nbase + wn * 64 + n * 16 + r0;   // bias index (v cols)
                int d = dglob - 1024;
                int tl = tb + wm * 64 + m * 16 + c0;
#pragma unroll
                for (int j = 0; j < 4; ++j) {
                    float v = acc[m][n][j] + bias[dglob + j];
                    vt[((size_t)bb * 512 + d + j) * 2048 + tl] = f2bf(v);
                }
            }
    }
}

// ------------- attention scores + softmax -> band probs P' -------------
// q-tile of 64 queries; key window of 128: kr = t0-64+j. Y: [4096][1536] = [q|k|sence].
__global__ __launch_bounds__(256) void attn_scores(const short* __restrict__ Y,
                                                   short* __restrict__ Pp) {
    __shared__ float sS[64][132];
    int tile = blockIdx.x;  // 0..63
    int b = tile >> 5;
    int t0 = (tile & 31) * 64;
    int s0 = tile * 64;
    int tid = threadIdx.x, lane = tid & 63, wave = tid >> 6;
    int wm = wave >> 1, wn = wave & 1;

    f32x4 acc[2][4] = {};
    const short* Q = Y;
    const short* Kb = Y + 512;

    int arow[2], brow[4];
#pragma unroll
    for (int m = 0; m < 2; ++m) arow[m] = s0 + wm * 32 + m * 16 + (lane & 15);
#pragma unroll
    for (int n = 0; n < 4; ++n) {
        int kr = t0 - 64 + wn * 64 + n * 16 + (lane & 15);
        if (kr < 0) kr = 0;  // masked later
        brow[n] = (b << 11) + kr;
    }
#pragma unroll
    for (int step = 0; step < 16; ++step) {
        int koff = step * 32 + (lane >> 4) * 8;
        sv8 af[2], bfr[4];
#pragma unroll
        for (int m = 0; m < 2; ++m)
            af[m] = *(const sv8*)(Q + (size_t)arow[m] * 1536 + koff);
#pragma unroll
        for (int n = 0; n < 4; ++n)
            bfr[n] = *(const sv8*)(Kb + (size_t)brow[n] * 1536 + koff);
#pragma unroll
        for (int m = 0; m < 2; ++m)
#pragma unroll
            for (int n = 0; n < 4; ++n)
                acc[m][n] = __builtin_amdgcn_mfma_f32_16x16x32_bf16(
                    af[m], bfr[n], acc[m][n], 0, 0, 0);
    }
    int r0 = (lane >> 4) * 4, c0 = lane & 15;
#pragma unroll
    for (int m = 0; m < 2; ++m)
#pragma unroll
        for (int n = 0; n < 4; ++n) {
            int jc = wn * 64 + n * 16 + c0;
#pragma unroll
            for (int j = 0; j < 4; ++j)
                sS[wm * 32 + m * 16 + r0 + j][jc] =
                    acc[m][n][j] * 0.04419417382415922f;  // 1/sqrt(512)
        }
    __syncthreads();

    // softmax: thread -> (q = tid>>2, quarter = tid&3)
    int q = tid >> 2, j0 = (tid & 3) * 32;
    float v[32];
    float mx = -1e30f;
    int jlo = q + 1;
    int jmin0 = 64 - t0;
    if (jmin0 > jlo) jlo = jmin0;
    int jhi = q + 64;
#pragma unroll
    for (int jj = 0; jj < 32; ++jj) {
        int j = j0 + jj;
        bool ok = (j >= jlo) && (j <= jhi);
        float s = ok ? sS[q][j] : -1e30f;
        v[jj] = s;
        mx = fmaxf(mx, s);
    }
    mx = fmaxf(mx, __shfl_xor(mx, 1));
    mx = fmaxf(mx, __shfl_xor(mx, 2));
    float sum = 0.f;
#pragma unroll
    for (int jj = 0; jj < 32; ++jj) {
        float e = (v[jj] > -1e29f) ? __expf(v[jj] - mx) : 0.f;
        v[jj] = e;
        sum += e;
    }
    sum += __shfl_xor(sum, 1);
    sum += __shfl_xor(sum, 2);
    float inv = 1.f / sum;
    short* dst = Pp + (size_t)tile * 8192 + q * 128 + j0;
#pragma unroll
    for (int k = 0; k < 4; ++k) {
        sv8 o;
#pragma unroll
        for (int e = 0; e < 8; ++e) o[e] = f2bf(v[k * 8 + e] * inv);
        *(sv8*)(dst + k * 8) = o;
    }
}

// ------------- PV: att[64 x 128-chunk] = P'[64x128] @ V[128 x d] via Vt -------------
__global__ __launch_bounds__(256) void attn_pv(const short* __restrict__ Pp,
                                               const short* __restrict__ Vt,
                                               short* __restrict__ att) {
    int tile = blockIdx.y, dchunk = blockIdx.x;  // 64 tiles x 4 d-chunks of 128
    int b = tile >> 5;
    int t0 = (tile & 31) * 64;
    int s0 = tile * 64;
    int tid = threadIdx.x, lane = tid & 63, wave = tid >> 6;
    int wm = wave >> 1, wn = wave & 1;

    f32x4 acc[2][4] = {};
    const short* Pbase = Pp + (size_t)tile * 8192;
#pragma unroll
    for (int ks = 0; ks < 4; ++ks) {
        int koff = ks * 32 + (lane >> 4) * 8;
        sv8 af[2], bfr[4];
#pragma unroll
        for (int m = 0; m < 2; ++m)
            af[m] = *(const sv8*)(Pbase + (wm * 32 + m * 16 + (lane & 15)) * 128 + koff);
#pragma unroll
        for (int n = 0; n < 4; ++n) {
            int d = dchunk * 128 + wn * 64 + n * 16 + (lane & 15);
            long off = (long)(b * 512 + d) * 2048 + (t0 - 64 + koff);  // <0 only where P'=0
            bfr[n] = *(const sv8*)(Vt + off);
        }
#pragma unroll
        for (int m = 0; m < 2; ++m)
#pragma unroll
            for (int n = 0; n < 4; ++n)
                acc[m][n] = __builtin_amdgcn_mfma_f32_16x16x32_bf16(
                    af[m], bfr[n], acc[m][n], 0, 0, 0);
    }
    int r0 = (lane >> 4) * 4, c0 = lane & 15;
#pragma unroll
    for (int m = 0; m < 2; ++m)
#pragma unroll
        for (int n = 0; n < 4; ++n) {
            int col = dchunk * 128 + wn * 64 + n * 16 + c0;
#pragma unroll
            for (int j = 0; j < 4; ++j) {
                int row = s0 + wm * 32 + m * 16 + r0 + j;
                att[(size_t)row * 512 + col] = f2bf(acc[m][n][j]);
            }
        }
}

// ------------- LN(read) + LN(sence) + GeLU -------------
__global__ __launch_bounds__(256) void ln_gelu(const short* __restrict__ readb,
                                               const short* __restrict__ Y,
                                               const float* __restrict__ gamma,
                                               const float* __restrict__ beta,
                                               float* __restrict__ out) {
    int s = blockIdx.x;
    int tid = threadIdx.x;
    const short* r = readb + (size_t)s * 512;
    const short* sn = Y + (size_t)s * 1536 + 1024;
    float r0 = bf2f(r[tid]), r1 = bf2f(r[tid + 256]);
    float s0 = bf2f(sn[tid]), s1 = bf2f(sn[tid + 256]);

    float v0 = r0 + r1, v1 = r0 * r0 + r1 * r1;
    float v2 = s0 + s1, v3 = s0 * s0 + s1 * s1;
#pragma unroll
    for (int off = 32; off; off >>= 1) {
        v0 += __shfl_xor(v0, off);
        v1 += __shfl_xor(v1, off);
        v2 += __shfl_xor(v2, off);
        v3 += __shfl_xor(v3, off);
    }
    __shared__ float red[4][4];
    int wave = tid >> 6, lane = tid & 63;
    if (lane == 0) {
        red[wave][0] = v0; red[wave][1] = v1; red[wave][2] = v2; red[wave][3] = v3;
    }
    __syncthreads();
    float t0 = red[0][0] + red[1][0] + red[2][0] + red[3][0];
    float t1 = red[0][1] + red[1][1] + red[2][1] + red[3][1];
    float t2 = red[0][2] + red[1][2] + red[2][2] + red[3][2];
    float t3 = red[0][3] + red[1][3] + red[2][3] + red[3][3];

    float mu_r = t0 * (1.f / 512.f);
    float var_r = t1 * (1.f / 512.f) - mu_r * mu_r;
    float is_r = rsqrtf(var_r + 1e-5f);
    float mu_s = t2 * (1.f / 512.f);
    float var_s = t3 * (1.f / 512.f) - mu_s * mu_s;
    float is_s = rsqrtf(var_s + 1e-5f);

    float g0 = gamma[tid], be0 = beta[tid];
    float g1 = gamma[tid + 256], be1 = beta[tid + 256];
    float x0 = (r0 - mu_r) * is_r * g0 + be0 + (s0 - mu_s) * is_s * g0 + be0;
    float x1 = (r1 - mu_r) * is_r * g1 + be1 + (s1 - mu_s) * is_s * g1 + be1;
    float y0 = 0.5f * x0 * (1.f + erff(x0 * 0.70710678118654752f));
    float y1 = 0.5f * x1 * (1.f + erff(x1 * 0.70710678118654752f));
    out[(size_t)s * 512 + tid] = y0;
    out[(size_t)s * 512 + tid + 256] = y1;
}

extern "C" void kernel_launch(void* const* d_in, const int* in_sizes, int n_in,
                              void* d_out, int out_size, void* d_ws, size_t ws_size,
                              hipStream_t stream) {
    const float* x  = (const float*)d_in[0];
    const float* Wq = (const float*)d_in[1];
    const float* bq = (const float*)d_in[2];
    const float* Wk = (const float*)d_in[3];
    const float* bk = (const float*)d_in[4];
    const float* Wv = (const float*)d_in[5];
    const float* bv = (const float*)d_in[6];
    const float* Wo = (const float*)d_in[7];
    const float* bo = (const float*)d_in[8];
    const float* Wr = (const float*)d_in[9];
    const float* br = (const float*)d_in[10];
    const float* gamma = (const float*)d_in[11];
    const float* beta  = (const float*)d_in[12];

    char* ws = (char*)d_ws;
    short* xb    = (short*)(ws + OFF_XB);
    short* wt    = (short*)(ws + OFF_WT);
    float* ball  = (float*)(ws + OFF_BIAS);
    short* Y     = (short*)(ws + OFF_Y);
    short* vtb   = (short*)(ws + OFF_VT);
    short* readb = (short*)(ws + OFF_READ);
    short* Pp    = (short*)(ws + OFF_PP);
    short* att   = (short*)(ws + OFF_ATT);   // overlays xb (dead after gemm1)

    cast_x<<<2048, 256, 0, stream>>>(x, xb, MTOT * DD / 4);
    prep_all<<<dim3(16, 16, 6), 256, 0, stream>>>(Wq, Wk, Wv, Wr, Wo, bq, bk, bv, br,
                                                  wt, ball);

    // one launch: Y=[q|k|sence] plus Vt (v cols, transposed via operand swap)
    gemm_bt<1><<<dim3(16, 32), 256, 0, stream>>>(xb, wt, ball, Y, 1536, vtb);

    attn_scores<<<64, 256, 0, stream>>>(Y, Pp);
    attn_pv<<<dim3(4, 64), 256, 0, stream>>>(Pp, vtb, att);

    // read = att @ Wo + bo (bf16 out)
    gemm_bt<0><<<dim3(4, 32), 256, 0, stream>>>(att, wt + (size_t)4 * 512 * 512, bo,
                                                readb, 512, nullptr);

    ln_gelu<<<4096, 256, 0, stream>>>(readb, Y, gamma, beta, (float*)d_out);
}

// Round 7
// 154.304 us; speedup vs baseline: 1.0469x; 1.0190x over previous
//
#include <hip/hip_runtime.h>
#include <hip/hip_bf16.h>
#include <math.h>

// Problem constants
#define BB 2
#define SS 2048
#define DD 512
#define MTOT 4096   // B*S

typedef __attribute__((ext_vector_type(8))) short sv8;   // 8 bf16
typedef __attribute__((ext_vector_type(4))) float f32x4;

// workspace layout (bytes)
static const size_t OFF_XB   = 0;               // bf16 x      [4096][512]   4 MB (dead after gemm1; att reuses)
static const size_t OFF_WT   = 4194304;         // bf16 Wt     [5][512][512] 2.5 MB ([q|k|v|r|o], [n][k])
static const size_t OFF_BIAS = 6815744;         // f32 bias    [2048]        8 KB (bq|bk|bv|br)
static const size_t OFF_Y    = 6823936;         // bf16 Y      [4096][1536]  12 MB (q|k|sence)
static const size_t OFF_VT   = 19406848;        // bf16 Vt     [2][512][2048] 4 MB (v transposed)
static const size_t OFF_READ = 23601152;        // bf16 read   [4096][512]   4 MB
static const size_t OFF_PP   = 27795456;        // bf16 P'     [64][64][128]  1 MB
static const size_t OFF_ATT  = 0;               // bf16 att    [4096][512]   4 MB (reuses XB)

static __device__ __forceinline__ float bf2f(short s) {
    unsigned u = ((unsigned)(unsigned short)s) << 16;
    return __builtin_bit_cast(float, u);
}
static __device__ __forceinline__ short f2bf(float f) {
    unsigned u = __builtin_bit_cast(unsigned, f);
    unsigned r = 0x7fffu + ((u >> 16) & 1u);
    u += r;
    return (short)(u >> 16);
}

// async global->LDS, 16B per lane; LDS dest is wave-uniform base (HW adds lane*16)
#define GLOAD_LDS16(gp, lp)                                                        \
    __builtin_amdgcn_global_load_lds(                                              \
        (const __attribute__((address_space(1))) unsigned*)(gp),                   \
        (__attribute__((address_space(3))) unsigned*)(lp), 16, 0, 0)

// ------------- prep: weights cast+transpose (z=0..4), cast_x + bias (z=5) -------------
__global__ __launch_bounds__(256) void prep_all(const float* __restrict__ x,
                                                const float* __restrict__ Wq,
                                                const float* __restrict__ Wk,
                                                const float* __restrict__ Wv,
                                                const float* __restrict__ Wr,
                                                const float* __restrict__ Wo,
                                                const float* __restrict__ bq,
                                                const float* __restrict__ bk,
                                                const float* __restrict__ bv,
                                                const float* __restrict__ br,
                                                short* __restrict__ xb,
                                                short* __restrict__ wt,
                                                float* __restrict__ ball) {
    int z = blockIdx.z;
    int tid = threadIdx.x;
    if (z == 5) {
        int flat = blockIdx.y * 16 + blockIdx.x;  // 0..255
        // bias concat (block 0 only)
        if (flat == 0) {
#pragma unroll
            for (int it = 0; it < 8; ++it) {
                int i = it * 256 + tid;  // 0..2047
                int sel = i >> 9;
                const float* src = (sel == 0) ? bq : (sel == 1) ? bk : (sel == 2) ? bv : br;
                ball[i] = src[i & 511];
            }
        }
        // cast x -> bf16, grid-stride over 524288 float4s
        for (int i = flat * 256 + tid; i < MTOT * DD / 4; i += 256 * 256) {
            float4 v = ((const float4*)x)[i];
            short4 o;
            o.x = f2bf(v.x); o.y = f2bf(v.y); o.z = f2bf(v.z); o.w = f2bf(v.w);
            ((short4*)xb)[i] = o;
        }
        return;
    }
    __shared__ float tile[32][33];
    const float* W = (z == 0) ? Wq : (z == 1) ? Wk : (z == 2) ? Wv : (z == 3) ? Wr : Wo;
    int k0 = blockIdx.y * 32, n0 = blockIdx.x * 32;
    int tx = tid & 31, ty = tid >> 5;  // ty in 0..7
    for (int r = ty; r < 32; r += 8)
        tile[r][tx] = W[(size_t)(k0 + r) * 512 + n0 + tx];
    __syncthreads();
    short* o = wt + (size_t)z * 512 * 512;
    for (int r = ty; r < 32; r += 8)
        o[(size_t)(n0 + r) * 512 + k0 + tx] = f2bf(tile[tx][r]);
}

// ------------- bf16 MFMA GEMM, global_load_lds staging, linear LDS -------------
// A: [M][512] bf16, Bt: [N][512] bf16. 128x128 tile, BK=64.
// GEMM1==0: plain: Cout[row*ldc+col] = f2bf(acc + bias[col]) (LDS-staged coalesced store).
// GEMM1==1: col remap for fused [q|k|v|r] output:
//   cols <1024 (q,k)  -> Y[row*1536 + col]
//   cols 1024..1535 (v) -> operand-swapped MFMA, transposed out to Vt[b][d][t]
//   cols >=1536 (r)    -> Y[row*1536 + col-512]
template <int GEMM1>
__global__ __launch_bounds__(256) void gemm_bt(const short* __restrict__ A,
                                               const short* __restrict__ Bt,
                                               const float* __restrict__ bias,
                                               short* __restrict__ Cout, int ldc,
                                               short* __restrict__ vt) {
    __shared__ __align__(16) short lbuf[2 * 128 * 64];  // lA | lB; reused as C-tile [128][128]
    short* lA = lbuf;
    short* lB = lbuf + 128 * 64;
    int tid = threadIdx.x;
    int mbase = blockIdx.y * 128;
    int nbase = blockIdx.x * 128;
    int lane = tid & 63, wave = tid >> 6;
    int wm = wave >> 1, wn = wave & 1;
    bool vswap = GEMM1 && (nbase >= 1024) && (nbase < 1536);

    f32x4 acc[4][4] = {};

    int srow = (lane >> 3);        // 0..7 within 8-row chunk
    int scol = (lane & 7) * 8;     // element offset (16B)

    for (int k0 = 0; k0 < 512; k0 += 64) {
#pragma unroll
        for (int c = 0; c < 4; ++c) {
            int ch = wave * 4 + c;  // 0..15, wave-uniform
            int row = ch * 8 + srow;
            GLOAD_LDS16(A + (size_t)(mbase + row) * 512 + k0 + scol, &lA[ch * 512]);
            GLOAD_LDS16(Bt + (size_t)(nbase + row) * 512 + k0 + scol, &lB[ch * 512]);
        }
        __syncthreads();
#pragma unroll
        for (int kk = 0; kk < 2; ++kk) {
            int koff = kk * 32 + (lane >> 4) * 8;
            sv8 af[4], bfr[4];
#pragma unroll
            for (int m = 0; m < 4; ++m)
                af[m] = *(const sv8*)&lA[(wm * 64 + m * 16 + (lane & 15)) * 64 + koff];
#pragma unroll
            for (int n = 0; n < 4; ++n)
                bfr[n] = *(const sv8*)&lB[(wn * 64 + n * 16 + (lane & 15)) * 64 + koff];
            if (!vswap) {
#pragma unroll
                for (int m = 0; m < 4; ++m)
#pragma unroll
                    for (int n = 0; n < 4; ++n)
                        acc[m][n] = __builtin_amdgcn_mfma_f32_16x16x32_bf16(
                            af[m], bfr[n], acc[m][n], 0, 0, 0);
            } else {  // swapped: acc holds the transposed tile
#pragma unroll
                for (int m = 0; m < 4; ++m)
#pragma unroll
                    for (int n = 0; n < 4; ++n)
                        acc[m][n] = __builtin_amdgcn_mfma_f32_16x16x32_bf16(
                            bfr[n], af[m], acc[m][n], 0, 0, 0);
            }
        }
        __syncthreads();  // also guards lbuf reuse as C-tile below
    }

    int r0 = (lane >> 4) * 4, c0 = lane & 15;
    if (!vswap) {
        // stage C tile (bias added) into LDS, then 16B-coalesced global stores
        short* sC = lbuf;  // [128][128]
#pragma unroll
        for (int m = 0; m < 4; ++m)
#pragma unroll
            for (int n = 0; n < 4; ++n) {
                int cl = wn * 64 + n * 16 + c0;
                float bv = bias[nbase + cl];
#pragma unroll
                for (int j = 0; j < 4; ++j) {
                    int rl = wm * 64 + m * 16 + r0 + j;
                    sC[rl * 128 + cl] = f2bf(acc[m][n][j] + bv);
                }
            }
        __syncthreads();
        int nybase = (GEMM1 && nbase >= 1536) ? nbase - 512 : nbase;
#pragma unroll
        for (int it = 0; it < 8; ++it) {
            int idx = it * 256 + tid;          // 0..2047
            int row = idx >> 4, slot = idx & 15;
            sv8 v = *(const sv8*)&sC[row * 128 + slot * 8];
            *(sv8*)&Cout[(size_t)(mbase + row) * ldc + nybase + slot * 8] = v;
        }
    } else {
        // Vt[b][d][t]: frag rows -> d (feature), frag cols -> t (token, 16-lane contiguous)
        int bb = mbase >> 11, tb = mbase & 2047;
#pragma unroll
        for (int m = 0; m < 4; ++m)
#pragma unroll
            for (int n = 0; n < 4; ++n) {
                int dglob = nbase + wn * 64 + n * 16 + r0;   // bias index (v cols)
                int d = dglob - 1024;
                int tl = tb + wm * 64 + m * 16 + c0;
#pragma unroll
                for (int j = 0; j < 4; ++j) {
                    float v = acc[m][n][j] + bias[dglob + j];
                    vt[((size_t)bb * 512 + d + j) * 2048 + tl] = f2bf(v);
                }
            }
    }
}

// ------------- attention scores + softmax -> band probs P' -------------
// q-tile of 64 queries; key window of 128: kr = t0-64+j. Y: [4096][1536] = [q|k|sence].
__global__ __launch_bounds__(256) void attn_scores(const short* __restrict__ Y,
                                                   short* __restrict__ Pp) {
    __shared__ float sS[64][132];
    int tile = blockIdx.x;  // 0..63
    int b = tile >> 5;
    int t0 = (tile & 31) * 64;
    int s0 = tile * 64;
    int tid = threadIdx.x, lane = tid & 63, wave = tid >> 6;
    int wm = wave >> 1, wn = wave & 1;

    f32x4 acc[2][4] = {};
    const short* Q = Y;
    const short* Kb = Y + 512;

    int arow[2], brow[4];
#pragma unroll
    for (int m = 0; m < 2; ++m) arow[m] = s0 + wm * 32 + m * 16 + (lane & 15);
#pragma unroll
    for (int n = 0; n < 4; ++n) {
        int kr = t0 - 64 + wn * 64 + n * 16 + (lane & 15);
        if (kr < 0) kr = 0;  // masked later
        brow[n] = (b << 11) + kr;
    }
#pragma unroll
    for (int step = 0; step < 16; ++step) {
        int koff = step * 32 + (lane >> 4) * 8;
        sv8 af[2], bfr[4];
#pragma unroll
        for (int m = 0; m < 2; ++m)
            af[m] = *(const sv8*)(Q + (size_t)arow[m] * 1536 + koff);
#pragma unroll
        for (int n = 0; n < 4; ++n)
            bfr[n] = *(const sv8*)(Kb + (size_t)brow[n] * 1536 + koff);
#pragma unroll
        for (int m = 0; m < 2; ++m)
#pragma unroll
            for (int n = 0; n < 4; ++n)
                acc[m][n] = __builtin_amdgcn_mfma_f32_16x16x32_bf16(
                    af[m], bfr[n], acc[m][n], 0, 0, 0);
    }
    int r0 = (lane >> 4) * 4, c0 = lane & 15;
#pragma unroll
    for (int m = 0; m < 2; ++m)
#pragma unroll
        for (int n = 0; n < 4; ++n) {
            int jc = wn * 64 + n * 16 + c0;
#pragma unroll
            for (int j = 0; j < 4; ++j)
                sS[wm * 32 + m * 16 + r0 + j][jc] =
                    acc[m][n][j] * 0.04419417382415922f;  // 1/sqrt(512)
        }
    __syncthreads();

    // softmax: thread -> (q = tid>>2, quarter = tid&3)
    int q = tid >> 2, j0 = (tid & 3) * 32;
    float v[32];
    float mx = -1e30f;
    int jlo = q + 1;
    int jmin0 = 64 - t0;
    if (jmin0 > jlo) jlo = jmin0;
    int jhi = q + 64;
#pragma unroll
    for (int jj = 0; jj < 32; ++jj) {
        int j = j0 + jj;
        bool ok = (j >= jlo) && (j <= jhi);
        float s = ok ? sS[q][j] : -1e30f;
        v[jj] = s;
        mx = fmaxf(mx, s);
    }
    mx = fmaxf(mx, __shfl_xor(mx, 1));
    mx = fmaxf(mx, __shfl_xor(mx, 2));
    float sum = 0.f;
#pragma unroll
    for (int jj = 0; jj < 32; ++jj) {
        float e = (v[jj] > -1e29f) ? __expf(v[jj] - mx) : 0.f;
        v[jj] = e;
        sum += e;
    }
    sum += __shfl_xor(sum, 1);
    sum += __shfl_xor(sum, 2);
    float inv = 1.f / sum;
    short* dst = Pp + (size_t)tile * 8192 + q * 128 + j0;
#pragma unroll
    for (int k = 0; k < 4; ++k) {
        sv8 o;
#pragma unroll
        for (int e = 0; e < 8; ++e) o[e] = f2bf(v[k * 8 + e] * inv);
        *(sv8*)(dst + k * 8) = o;
    }
}

// ------------- PV: att[64 x 128-chunk] = P'[64x128] @ V[128 x d] via Vt -------------
__global__ __launch_bounds__(256) void attn_pv(const short* __restrict__ Pp,
                                               const short* __restrict__ Vt,
                                               short* __restrict__ att) {
    int tile = blockIdx.y, dchunk = blockIdx.x;  // 64 tiles x 4 d-chunks of 128
    int b = tile >> 5;
    int t0 = (tile & 31) * 64;
    int s0 = tile * 64;
    int tid = threadIdx.x, lane = tid & 63, wave = tid >> 6;
    int wm = wave >> 1, wn = wave & 1;

    f32x4 acc[2][4] = {};
    const short* Pbase = Pp + (size_t)tile * 8192;
#pragma unroll
    for (int ks = 0; ks < 4; ++ks) {
        int koff = ks * 32 + (lane >> 4) * 8;
        sv8 af[2], bfr[4];
#pragma unroll
        for (int m = 0; m < 2; ++m)
            af[m] = *(const sv8*)(Pbase + (wm * 32 + m * 16 + (lane & 15)) * 128 + koff);
#pragma unroll
        for (int n = 0; n < 4; ++n) {
            int d = dchunk * 128 + wn * 64 + n * 16 + (lane & 15);
            long off = (long)(b * 512 + d) * 2048 + (t0 - 64 + koff);  // <0 only where P'=0
            bfr[n] = *(const sv8*)(Vt + off);
        }
#pragma unroll
        for (int m = 0; m < 2; ++m)
#pragma unroll
            for (int n = 0; n < 4; ++n)
                acc[m][n] = __builtin_amdgcn_mfma_f32_16x16x32_bf16(
                    af[m], bfr[n], acc[m][n], 0, 0, 0);
    }
    int r0 = (lane >> 4) * 4, c0 = lane & 15;
#pragma unroll
    for (int m = 0; m < 2; ++m)
#pragma unroll
        for (int n = 0; n < 4; ++n) {
            int col = dchunk * 128 + wn * 64 + n * 16 + c0;
#pragma unroll
            for (int j = 0; j < 4; ++j) {
                int row = s0 + wm * 32 + m * 16 + r0 + j;
                att[(size_t)row * 512 + col] = f2bf(acc[m][n][j]);
            }
        }
}

// ------------- LN(read) + LN(sence) + GeLU: one wave per row, sv8 loads -------------
__global__ __launch_bounds__(256) void ln_gelu(const short* __restrict__ readb,
                                               const short* __restrict__ Y,
                                               const float* __restrict__ gamma,
                                               const float* __restrict__ beta,
                                               float* __restrict__ out) {
    int row = blockIdx.x * 4 + (threadIdx.x >> 6);  // 4 waves = 4 rows per block
    int lane = threadIdx.x & 63;
    sv8 rv = *(const sv8*)(readb + (size_t)row * 512 + lane * 8);
    sv8 sv = *(const sv8*)(Y + (size_t)row * 1536 + 1024 + lane * 8);
    float rf[8], sf[8];
    float sr = 0.f, sr2 = 0.f, ss = 0.f, ss2 = 0.f;
#pragma unroll
    for (int e = 0; e < 8; ++e) {
        rf[e] = bf2f(rv[e]); sf[e] = bf2f(sv[e]);
        sr += rf[e]; sr2 += rf[e] * rf[e];
        ss += sf[e]; ss2 += sf[e] * sf[e];
    }
#pragma unroll
    for (int off = 32; off; off >>= 1) {
        sr += __shfl_xor(sr, off);
        sr2 += __shfl_xor(sr2, off);
        ss += __shfl_xor(ss, off);
        ss2 += __shfl_xor(ss2, off);
    }
    float mu_r = sr * (1.f / 512.f);
    float is_r = rsqrtf(sr2 * (1.f / 512.f) - mu_r * mu_r + 1e-5f);
    float mu_s = ss * (1.f / 512.f);
    float is_s = rsqrtf(ss2 * (1.f / 512.f) - mu_s * mu_s + 1e-5f);

    float4 ga = ((const float4*)gamma)[lane * 2];
    float4 gb = ((const float4*)gamma)[lane * 2 + 1];
    float4 ba = ((const float4*)beta)[lane * 2];
    float4 bb = ((const float4*)beta)[lane * 2 + 1];
    float g[8] = {ga.x, ga.y, ga.z, ga.w, gb.x, gb.y, gb.z, gb.w};
    float be[8] = {ba.x, ba.y, ba.z, ba.w, bb.x, bb.y, bb.z, bb.w};

    float y[8];
#pragma unroll
    for (int e = 0; e < 8; ++e) {
        float xv = (rf[e] - mu_r) * is_r * g[e] + be[e] +
                   (sf[e] - mu_s) * is_s * g[e] + be[e];
        y[e] = 0.5f * xv * (1.f + erff(xv * 0.70710678118654752f));
    }
    float* o = out + (size_t)row * 512 + lane * 8;
    ((float4*)o)[0] = make_float4(y[0], y[1], y[2], y[3]);
    ((float4*)o)[1] = make_float4(y[4], y[5], y[6], y[7]);
}

extern "C" void kernel_launch(void* const* d_in, const int* in_sizes, int n_in,
                              void* d_out, int out_size, void* d_ws, size_t ws_size,
                              hipStream_t stream) {
    const float* x  = (const float*)d_in[0];
    const float* Wq = (const float*)d_in[1];
    const float* bq = (const float*)d_in[2];
    const float* Wk = (const float*)d_in[3];
    const float* bk = (const float*)d_in[4];
    const float* Wv = (const float*)d_in[5];
    const float* bv = (const float*)d_in[6];
    const float* Wo = (const float*)d_in[7];
    const float* bo = (const float*)d_in[8];
    const float* Wr = (const float*)d_in[9];
    const float* br = (const float*)d_in[10];
    const float* gamma = (const float*)d_in[11];
    const float* beta  = (const float*)d_in[12];

    char* ws = (char*)d_ws;
    short* xb    = (short*)(ws + OFF_XB);
    short* wt    = (short*)(ws + OFF_WT);
    float* ball  = (float*)(ws + OFF_BIAS);
    short* Y     = (short*)(ws + OFF_Y);
    short* vtb   = (short*)(ws + OFF_VT);
    short* readb = (short*)(ws + OFF_READ);
    short* Pp    = (short*)(ws + OFF_PP);
    short* att   = (short*)(ws + OFF_ATT);   // overlays xb (dead after gemm1)

    prep_all<<<dim3(16, 16, 6), 256, 0, stream>>>(x, Wq, Wk, Wv, Wr, Wo,
                                                  bq, bk, bv, br, xb, wt, ball);

    // one launch: Y=[q|k|sence] plus Vt (v cols, transposed via operand swap)
    gemm_bt<1><<<dim3(16, 32), 256, 0, stream>>>(xb, wt, ball, Y, 1536, vtb);

    attn_scores<<<64, 256, 0, stream>>>(Y, Pp);
    attn_pv<<<dim3(4, 64), 256, 0, stream>>>(Pp, vtb, att);

    // read = att @ Wo + bo (bf16 out)
    gemm_bt<0><<<dim3(4, 32), 256, 0, stream>>>(att, wt + (size_t)4 * 512 * 512, bo,
                                                readb, 512, nullptr);

    ln_gelu<<<1024, 256, 0, stream>>>(readb, Y, gamma, beta, (float*)d_out);
}